// Round 10
// baseline (114.547 us; speedup 1.0000x reference)
//
#include <hip/hip_runtime.h>
#include <math.h>

#define B_N 4096
#define M_N 256
#define D_N 256
#define ROWS 4                      // rows per k_main block
#define GRID_MAIN (B_N / ROWS)
#define NSLOT 64                    // partial-sum slots (1 per 64B line)
#define BLK_PER_SLOT (GRID_MAIN / NSLOT)

constexpr float TAU_   = 0.2f;
constexpr float LAM_   = 8.0f;
constexpr float TOPO_  = 0.5f;
constexpr float LEN_C_ = 0.01f;
constexpr float SP_C_  = 0.001f;
constexpr float LOG2E_ = 1.44269504088896340736f;
constexpr float KSC    = LOG2E_ / TAU_;
constexpr float KL     = LOG2E_ / LAM_;
constexpr float C0_    = 133.0f;    // fixed exponent center: dist ~18.5 -> sc ~133

// ws float layout:
// [4]          cnt2 (uint, single)
// [16..272)    degree[256]
// [512..768)   wnorm[256]
// [1024..1280) pPart[256]
// [1280..1536) wpdPart[256]
// [2048..3072) S_slot[64] strided 16 floats (64B line each)
// [4096..5120) cnt1[64]  (uint) strided 16
// [8192..73728) wT[256*256]  (D x M transpose)

__device__ __forceinline__ float wave_reduce_sum(float v) {
#pragma unroll
  for (int off = 1; off < 64; off <<= 1) v += __shfl_xor(v, off, 64);
  return v;
}

// sigmoid pair-combine step: s += (t+2)/( (t+1) + iv2*ep ), t = iv*es
__device__ __forceinline__ void rank_pair(float iv, float iv2, float es,
                                          float ep, float& s) {
  float t = iv * es;
  s = fmaf(t + 2.0f, __builtin_amdgcn_rcpf(fmaf(iv2, ep, t + 1.0f)), s);
}

// Dispatch 1: blocks 0..255 transpose w -> wT + wnorm + zero accumulators;
//             blocks 256..511 edge stats (direct proto-dist; self-contained).
__global__ __launch_bounds__(256) void k_prep(const float* __restrict__ w,
                                              const float* __restrict__ E,
                                              float* __restrict__ ws) {
  int tid = threadIdx.x;
  if (blockIdx.x < M_N) {
    float* wT = ws + 8192;
    int j = blockIdx.x, d = tid;
    float v = w[j * D_N + d];
    wT[d * M_N + j] = v;
    float s = wave_reduce_sum(v * v);
    __shared__ float red[4];
    if ((d & 63) == 0) red[d >> 6] = s;
    if (j == 0) {
      if (d < 16) ws[d] = 0.0f;                       // cnt2 etc.
      if (d < NSLOT) {
        ws[2048 + 16 * d] = 0.0f;                     // S_slot
        ((unsigned*)ws)[4096 + 16 * d] = 0u;          // cnt1
      }
    }
    __syncthreads();
    if (d == 0) ws[512 + j] = red[0] + red[1] + red[2] + red[3];
  } else {
    int j = blockIdx.x - M_N;
    int k = tid;
    __shared__ __align__(16) float swj[D_N];
    __shared__ float redp[4], redw[4];
    swj[k] = w[j * D_N + k];
    __syncthreads();

    float l = 0.5f * (E[j * M_N + k] + E[k * M_N + j]);
    float p = __builtin_amdgcn_rcpf(1.0f + __builtin_amdgcn_exp2f(-l * LOG2E_));
    if (k == j) p = 0.0f;

    float pd = 0.0f;
    const float4* wr = (const float4*)(w + (size_t)k * D_N);
    const float4* sw = (const float4*)swj;
#pragma unroll 8
    for (int i = 0; i < D_N / 4; i++) {
      float4 a = wr[i], b = sw[i];
      float dx = a.x - b.x, dy = a.y - b.y, dz = a.z - b.z, dw = a.w - b.w;
      pd += dx * dx + dy * dy + dz * dz + dw * dw;
    }

    float sp  = wave_reduce_sum(p);
    float spd = wave_reduce_sum(p * pd);
    if ((k & 63) == 0) { redp[k >> 6] = sp; redw[k >> 6] = spd; }
    __syncthreads();
    if (k == 0) {
      float tp = redp[0] + redp[1] + redp[2] + redp[3];
      float tw = redw[0] + redw[1] + redw[2] + redw[3];
      ws[16 + j]   = tp * (1.0f / (float)(M_N - 1));
      ws[1024 + j] = tp;
      ws[1280 + j] = tw;
    }
  }
}

// Dispatch 2: fused GEMM + soft-rank, software-pipelined:
//   GEMM(rows01) ; [GEMM(rows23) interleaved with rank(rows01)] ; rank(rows23)
__global__ __launch_bounds__(256) void k_main(const float* __restrict__ data,
                                              float* __restrict__ ws,
                                              float* __restrict__ out) {
  const float* wT     = ws + 8192;
  const float* wnorm  = ws + 512;
  const float* degree = ws + 16;
  float* S_slot  = ws + 2048;                 // stride 16 floats
  unsigned* cnt1 = (unsigned*)ws + 4096;      // stride 16
  unsigned* cnt2 = (unsigned*)ws + 4;

  __shared__ __align__(16) float ew[ROWS][M_N];   // e-values per row
  __shared__ __align__(16) float ewp[ROWS][M_N];  // pairs: [2p]=es, [2p+1]=ep
  __shared__ float rednrm[ROWS][4];
  __shared__ float snrm[ROWS];
  __shared__ float redf[4], redp[4], redw[4];
  __shared__ int isLast;

  const int tid  = threadIdx.x;
  const int wv_  = tid >> 6;
  const int lane = tid & 63;
  const int b0   = blockIdx.x * ROWS;

  // ---- Phase A: row norms ----
#pragma unroll
  for (int r = 0; r < ROWS; r++) {
    float x = data[(size_t)(b0 + r) * D_N + tid];
    float s = wave_reduce_sum(x * x);
    if (lane == 0) rednrm[r][wv_] = s;
  }
  __syncthreads();
  if (tid < ROWS)
    snrm[tid] = rednrm[tid][0] + rednrm[tid][1] + rednrm[tid][2] + rednrm[tid][3];

  const float4* x0 = (const float4*)(data + (size_t)(b0 + 0) * D_N);
  const float4* x1 = (const float4*)(data + (size_t)(b0 + 1) * D_N);
  const float4* x2 = (const float4*)(data + (size_t)(b0 + 2) * D_N);
  const float4* x3 = (const float4*)(data + (size_t)(b0 + 3) * D_N);

  // ---- Phase B: GEMM rows 0,1 (deep unroll: many loads in flight) ----
  float a0 = 0.f, a1 = 0.f;
#pragma unroll 8
  for (int d4 = 0; d4 < D_N / 4; d4++) {
    const float* p = wT + (size_t)(4 * d4) * M_N + tid;
    float w0 = p[0], w1 = p[M_N], w2 = p[2 * M_N], w3 = p[3 * M_N];
    float4 xa = x0[d4], xb = x1[d4];
    a0 = fmaf(xa.x, w0, a0); a0 = fmaf(xa.y, w1, a0);
    a0 = fmaf(xa.z, w2, a0); a0 = fmaf(xa.w, w3, a0);
    a1 = fmaf(xb.x, w0, a1); a1 = fmaf(xb.y, w1, a1);
    a1 = fmaf(xb.z, w2, a1); a1 = fmaf(xb.w, w3, a1);
  }
  __syncthreads();   // snrm visible

  float wn = wnorm[tid];
  float dist[ROWS], iv[ROWS], iv2[ROWS];
#pragma unroll
  for (int r = 0; r < 2; r++) {
    float a = (r == 0) ? a0 : a1;
    float sq = snrm[r] - 2.0f * a + wn;
    dist[r] = sqrtf(fmaxf(sq, 0.0f));
    float sc = dist[r] * KSC;
    ew[r][tid] = __builtin_amdgcn_exp2f(sc - C0_);
    iv[r]      = __builtin_amdgcn_exp2f(C0_ - sc);
    iv2[r]     = iv[r] * iv[r];
  }
  __syncthreads();

  // pair terms rows 0,1: 256 slots, one per thread
  {
    int r = tid >> 7, idx = tid & 127;
    float ea = ew[r][2 * idx], eb = ew[r][2 * idx + 1];
    ewp[r][2 * idx]     = ea + eb;
    ewp[r][2 * idx + 1] = ea * eb;
  }
  __syncthreads();

  // ---- Phase C: GEMM rows 2,3 interleaved with rank rows 0,1 ----
  // Per group: issue 16 wT loads; run 4 k4-groups of rank VALU (~covers L2
  // latency); then consume the loads for rows-2,3 fma.
  float a2 = 0.f, a3 = 0.f;
  float s0 = 0.f, s1 = 0.f;
  const float4* q0 = (const float4*)(&ewp[0][0]);
  const float4* q1 = (const float4*)(&ewp[1][0]);
  float iv0 = iv[0], iv20 = iv2[0], iv1 = iv[1], iv21 = iv2[1];
#pragma unroll 2
  for (int g = 0; g < 16; g++) {
    // (1) issue loads for d = 16g .. 16g+15
    float wreg[16];
    const float* p = wT + (size_t)(16 * g) * M_N + tid;
#pragma unroll
    for (int i = 0; i < 16; i++) wreg[i] = p[(size_t)i * M_N];
    // (2) rank rows 0,1 for k4 = 4g .. 4g+3
#pragma unroll
    for (int k4 = 4 * g; k4 < 4 * g + 4; k4++) {
      float4 qa = q0[k4];
      rank_pair(iv0, iv20, qa.x, qa.y, s0);
      rank_pair(iv0, iv20, qa.z, qa.w, s0);
      float4 qb = q1[k4];
      rank_pair(iv1, iv21, qb.x, qb.y, s1);
      rank_pair(iv1, iv21, qb.z, qb.w, s1);
    }
    // (3) consume loads: rows 2,3 fma for d4 = 4g .. 4g+3
#pragma unroll
    for (int i4 = 0; i4 < 4; i4++) {
      float4 xc = x2[4 * g + i4];
      float4 xd = x3[4 * g + i4];
      a2 = fmaf(xc.x, wreg[4 * i4 + 0], a2);
      a2 = fmaf(xc.y, wreg[4 * i4 + 1], a2);
      a2 = fmaf(xc.z, wreg[4 * i4 + 2], a2);
      a2 = fmaf(xc.w, wreg[4 * i4 + 3], a2);
      a3 = fmaf(xd.x, wreg[4 * i4 + 0], a3);
      a3 = fmaf(xd.y, wreg[4 * i4 + 1], a3);
      a3 = fmaf(xd.z, wreg[4 * i4 + 2], a3);
      a3 = fmaf(xd.w, wreg[4 * i4 + 3], a3);
    }
  }

#pragma unroll
  for (int r = 2; r < 4; r++) {
    float a = (r == 2) ? a2 : a3;
    float sq = snrm[r] - 2.0f * a + wn;
    dist[r] = sqrtf(fmaxf(sq, 0.0f));
    float sc = dist[r] * KSC;
    ew[r][tid] = __builtin_amdgcn_exp2f(sc - C0_);
    iv[r]      = __builtin_amdgcn_exp2f(C0_ - sc);
    iv2[r]     = iv[r] * iv[r];
  }
  __syncthreads();

  // pair terms rows 2,3
  {
    int r = 2 + (tid >> 7), idx = tid & 127;
    float ea = ew[r][2 * idx], eb = ew[r][2 * idx + 1];
    ewp[r][2 * idx]     = ea + eb;
    ewp[r][2 * idx + 1] = ea * eb;
  }
  __syncthreads();

  // ---- Phase D: rank rows 2,3 ----
  float s2 = 0.f, s3 = 0.f;
  const float4* q2 = (const float4*)(&ewp[2][0]);
  const float4* q3 = (const float4*)(&ewp[3][0]);
  float iv_2 = iv[2], iv22 = iv2[2], iv_3 = iv[3], iv23 = iv2[3];
#pragma unroll 8
  for (int k4 = 0; k4 < M_N / 4; k4++) {
    float4 qa = q2[k4];
    rank_pair(iv_2, iv22, qa.x, qa.y, s2);
    rank_pair(iv_2, iv22, qa.z, qa.w, s2);
    float4 qb = q3[k4];
    rank_pair(iv_3, iv23, qb.x, qb.y, s3);
    rank_pair(iv_3, iv23, qb.z, qb.w, s3);
  }

  // ---- Epilogue: neighborhood * dist * (1 + TOPO*degree); diag == 0.5 ----
  float fj = 1.0f + TOPO_ * degree[tid];
  float ssum[ROWS] = {s0, s1, s2, s3};
  float tl = 0.0f;
#pragma unroll
  for (int r = 0; r < ROWS; r++) {
    float nb = __builtin_amdgcn_exp2f((0.5f - ssum[r]) * KL);
    tl = fmaf(nb * dist[r], fj, tl);
  }

  float bs = wave_reduce_sum(tl);
  if (lane == 0) redf[wv_] = bs;
  __syncthreads();
  if (tid == 0) {
    float tot = redf[0] + redf[1] + redf[2] + redf[3];
    int slot = (int)(blockIdx.x & (NSLOT - 1));
    float old = atomicAdd(&S_slot[16 * slot], tot);
    asm volatile("" : "+v"(old));   // consume: slot-add committed before cnt1
    int last = 0;
    unsigned t1 = atomicAdd(&cnt1[16 * slot], 1u);
    if (t1 == (unsigned)(BLK_PER_SLOT - 1)) {        // slot closed
      unsigned t2 = atomicAdd(cnt2, 1u);             // only 64 ever reach here
      last = (t2 == (unsigned)(NSLOT - 1)) ? 1 : 0;  // all slots closed
    }
    isLast = last;
  }
  __syncthreads();

  if (isLast) {
    float p  = ws[1024 + tid];
    float wd = ws[1280 + tid];
    float rp = wave_reduce_sum(p);
    float rw = wave_reduce_sum(wd);
    if (lane == 0) { redp[wv_] = rp; redw[wv_] = rw; }
    float sd = 0.0f;
    if (wv_ == 0) {
      float v = atomicAdd(&S_slot[16 * lane], 0.0f);  // coherent slot read
      sd = wave_reduce_sum(v);
    }
    __syncthreads();
    if (tid == 0) {
      float Sp   = redp[0] + redp[1] + redp[2] + redp[3];
      float Swpd = redw[0] + redw[1] + redw[2] + redw[3];
      float data_term = sd * (1.0f / ((float)B_N * (float)M_N));
      float wl = Swpd / (Sp + 1e-8f);
      float sparsity = Sp * (1.0f / ((float)M_N * (float)M_N));
      out[0] = data_term + LEN_C_ * wl + SP_C_ * sparsity;
    }
  }
}

extern "C" void kernel_launch(void* const* d_in, const int* in_sizes, int n_in,
                              void* d_out, int out_size, void* d_ws, size_t ws_size,
                              hipStream_t stream) {
  const float* data = (const float*)d_in[0];
  const float* w    = (const float*)d_in[1];
  const float* E    = (const float*)d_in[2];
  float* ws = (float*)d_ws;

  k_prep<<<2 * M_N, 256, 0, stream>>>(w, E, ws);
  k_main<<<GRID_MAIN, 256, 0, stream>>>(data, ws, (float*)d_out);
}

// Round 11
// 108.538 us; speedup vs baseline: 1.0554x; 1.0554x over previous
//
#include <hip/hip_runtime.h>
#include <math.h>

#define B_N 4096
#define M_N 256
#define D_N 256
#define ROWS 2                      // rows per k_main block (8 blocks/CU TLP)
#define GRID_MAIN (B_N / ROWS)
#define NSLOT 64                    // partial-sum slots (1 per 64B line)
#define BLK_PER_SLOT (GRID_MAIN / NSLOT)

constexpr float TAU_   = 0.2f;
constexpr float LAM_   = 8.0f;
constexpr float TOPO_  = 0.5f;
constexpr float LEN_C_ = 0.01f;
constexpr float SP_C_  = 0.001f;
constexpr float LOG2E_ = 1.44269504088896340736f;
constexpr float KSC    = LOG2E_ / TAU_;
constexpr float KL     = LOG2E_ / LAM_;
constexpr float C0_    = 133.0f;    // fixed exponent center: dist ~18.5 -> sc ~133

// ws float layout:
// [4]          cnt2 (uint, single)
// [16..272)    degree[256]
// [512..768)   wnorm[256]
// [1024..1280) pPart[256]
// [1280..1536) wpdPart[256]
// [2048..3072) S_slot[64] strided 16 floats (64B line each)
// [4096..5120) cnt1[64]  (uint) strided 16
// [8192..73728) wT[256*256]  (D x M transpose)

__device__ __forceinline__ float wave_reduce_sum(float v) {
#pragma unroll
  for (int off = 1; off < 64; off <<= 1) v += __shfl_xor(v, off, 64);
  return v;
}

// sigmoid pair-combine step: s += (t+2)/( (t+1) + iv2*ep ), t = iv*es
__device__ __forceinline__ void rank_pair(float iv, float iv2, float es,
                                          float ep, float& s) {
  float t = iv * es;
  s = fmaf(t + 2.0f, __builtin_amdgcn_rcpf(fmaf(iv2, ep, t + 1.0f)), s);
}

// Dispatch 1: blocks 0..255 transpose w -> wT + wnorm + zero accumulators;
//             blocks 256..511 edge stats (direct proto-dist; self-contained).
__global__ __launch_bounds__(256) void k_prep(const float* __restrict__ w,
                                              const float* __restrict__ E,
                                              float* __restrict__ ws) {
  int tid = threadIdx.x;
  if (blockIdx.x < M_N) {
    float* wT = ws + 8192;
    int j = blockIdx.x, d = tid;
    float v = w[j * D_N + d];
    wT[d * M_N + j] = v;
    float s = wave_reduce_sum(v * v);
    __shared__ float red[4];
    if ((d & 63) == 0) red[d >> 6] = s;
    if (j == 0) {
      if (d < 16) ws[d] = 0.0f;                       // cnt2 etc.
      if (d < NSLOT) {
        ws[2048 + 16 * d] = 0.0f;                     // S_slot
        ((unsigned*)ws)[4096 + 16 * d] = 0u;          // cnt1
      }
    }
    __syncthreads();
    if (d == 0) ws[512 + j] = red[0] + red[1] + red[2] + red[3];
  } else {
    int j = blockIdx.x - M_N;
    int k = tid;
    __shared__ __align__(16) float swj[D_N];
    __shared__ float redp[4], redw[4];
    swj[k] = w[j * D_N + k];
    __syncthreads();

    float l = 0.5f * (E[j * M_N + k] + E[k * M_N + j]);
    float p = __builtin_amdgcn_rcpf(1.0f + __builtin_amdgcn_exp2f(-l * LOG2E_));
    if (k == j) p = 0.0f;

    float pd = 0.0f;
    const float4* wr = (const float4*)(w + (size_t)k * D_N);
    const float4* sw = (const float4*)swj;
#pragma unroll 8
    for (int i = 0; i < D_N / 4; i++) {
      float4 a = wr[i], b = sw[i];
      float dx = a.x - b.x, dy = a.y - b.y, dz = a.z - b.z, dw = a.w - b.w;
      pd += dx * dx + dy * dy + dz * dz + dw * dw;
    }

    float sp  = wave_reduce_sum(p);
    float spd = wave_reduce_sum(p * pd);
    if ((k & 63) == 0) { redp[k >> 6] = sp; redw[k >> 6] = spd; }
    __syncthreads();
    if (k == 0) {
      float tp = redp[0] + redp[1] + redp[2] + redp[3];
      float tw = redw[0] + redw[1] + redw[2] + redw[3];
      ws[16 + j]   = tp * (1.0f / (float)(M_N - 1));
      ws[1024 + j] = tp;
      ws[1280 + j] = tw;
    }
  }
}

// Dispatch 2: fused GEMM + soft-rank (R9 structure, ROWS=2 for TLP overlap).
// Thread owns column j=tid for 2 rows; dist stays in registers; rank uses
// hoisted per-row (es,ep) pair terms; hierarchical distributed atomics.
__global__ __launch_bounds__(256) void k_main(const float* __restrict__ data,
                                              float* __restrict__ ws,
                                              float* __restrict__ out) {
  const float* wT     = ws + 8192;
  const float* wnorm  = ws + 512;
  const float* degree = ws + 16;
  float* S_slot  = ws + 2048;                 // stride 16 floats
  unsigned* cnt1 = (unsigned*)ws + 4096;      // stride 16
  unsigned* cnt2 = (unsigned*)ws + 4;

  __shared__ __align__(16) float ew[ROWS][M_N];   // e-values per row
  __shared__ __align__(16) float ewp[ROWS][M_N];  // pairs: [2p]=es, [2p+1]=ep
  __shared__ float rednrm[ROWS][4];
  __shared__ float snrm[ROWS];
  __shared__ float redf[4], redp[4], redw[4];
  __shared__ int isLast;

  const int tid  = threadIdx.x;
  const int wv_  = tid >> 6;
  const int lane = tid & 63;
  const int b0   = blockIdx.x * ROWS;

  // row norms
#pragma unroll
  for (int r = 0; r < ROWS; r++) {
    float x = data[(size_t)(b0 + r) * D_N + tid];
    float s = wave_reduce_sum(x * x);
    if (lane == 0) rednrm[r][wv_] = s;
  }
  __syncthreads();
  if (tid < ROWS)
    snrm[tid] = rednrm[tid][0] + rednrm[tid][1] + rednrm[tid][2] + rednrm[tid][3];

  // GEMM: x rows block-uniform (s_load float4); wT coalesced per thread
  const float4* x0 = (const float4*)(data + (size_t)(b0 + 0) * D_N);
  const float4* x1 = (const float4*)(data + (size_t)(b0 + 1) * D_N);
  float a0 = 0.f, a1 = 0.f;
#pragma unroll 8
  for (int d4 = 0; d4 < D_N / 4; d4++) {
    const float* p = wT + (size_t)(4 * d4) * M_N + tid;
    float w0 = p[0], w1 = p[M_N], w2 = p[2 * M_N], w3 = p[3 * M_N];
    float4 xa = x0[d4], xb = x1[d4];
    a0 = fmaf(xa.x, w0, a0); a0 = fmaf(xa.y, w1, a0);
    a0 = fmaf(xa.z, w2, a0); a0 = fmaf(xa.w, w3, a0);
    a1 = fmaf(xb.x, w0, a1); a1 = fmaf(xb.y, w1, a1);
    a1 = fmaf(xb.z, w2, a1); a1 = fmaf(xb.w, w3, a1);
  }
  __syncthreads();   // snrm visible

  // distances + e-values (dist stays in registers for j = tid)
  float wn = wnorm[tid];
  float acc[ROWS] = {a0, a1};
  float dist[ROWS], iv[ROWS], iv2[ROWS];
#pragma unroll
  for (int r = 0; r < ROWS; r++) {
    float sq = snrm[r] - 2.0f * acc[r] + wn;
    dist[r] = sqrtf(fmaxf(sq, 0.0f));
    float sc = dist[r] * KSC;
    ew[r][tid] = __builtin_amdgcn_exp2f(sc - C0_);
    iv[r]      = __builtin_amdgcn_exp2f(C0_ - sc);
    iv2[r]     = iv[r] * iv[r];
  }
  __syncthreads();

  // hoisted pair terms: 2 rows x 128 pairs = 256 slots, one per thread
  {
    int r = tid >> 7, idx = tid & 127;
    float ea = ew[r][2 * idx], eb = ew[r][2 * idx + 1];
    ewp[r][2 * idx]     = ea + eb;
    ewp[r][2 * idx + 1] = ea * eb;
  }
  __syncthreads();

  // rank: per row, sum_k sigmoid((d_j-d_k)/tau), pair-combined
  float s0 = 0.f, s1 = 0.f;
  const float4* q0 = (const float4*)(&ewp[0][0]);
  const float4* q1 = (const float4*)(&ewp[1][0]);
  float iv0 = iv[0], iv20 = iv2[0], iv1 = iv[1], iv21 = iv2[1];
#pragma unroll 8
  for (int k4 = 0; k4 < M_N / 4; k4++) {
    float4 qa = q0[k4];                        // (es_a, ep_a, es_b, ep_b)
    rank_pair(iv0, iv20, qa.x, qa.y, s0);
    rank_pair(iv0, iv20, qa.z, qa.w, s0);
    float4 qb = q1[k4];
    rank_pair(iv1, iv21, qb.x, qb.y, s1);
    rank_pair(iv1, iv21, qb.z, qb.w, s1);
  }

  // epilogue: neighborhood * dist * (1 + TOPO*degree); diagonal == 0.5
  float fj = 1.0f + TOPO_ * degree[tid];
  float nb0 = __builtin_amdgcn_exp2f((0.5f - s0) * KL);
  float nb1 = __builtin_amdgcn_exp2f((0.5f - s1) * KL);
  float tl = fmaf(nb0 * dist[0], fj, nb1 * dist[1] * fj);

  float bs = wave_reduce_sum(tl);
  if (lane == 0) redf[wv_] = bs;
  __syncthreads();
  if (tid == 0) {
    float tot = redf[0] + redf[1] + redf[2] + redf[3];
    int slot = (int)(blockIdx.x & (NSLOT - 1));
    float old = atomicAdd(&S_slot[16 * slot], tot);
    asm volatile("" : "+v"(old));   // consume: slot-add committed before cnt1
    int last = 0;
    unsigned t1 = atomicAdd(&cnt1[16 * slot], 1u);
    if (t1 == (unsigned)(BLK_PER_SLOT - 1)) {        // slot closed
      unsigned t2 = atomicAdd(cnt2, 1u);             // only 64 ever reach here
      last = (t2 == (unsigned)(NSLOT - 1)) ? 1 : 0;  // all slots closed
    }
    isLast = last;
  }
  __syncthreads();

  if (isLast) {
    float p  = ws[1024 + tid];
    float wd = ws[1280 + tid];
    float rp = wave_reduce_sum(p);
    float rw = wave_reduce_sum(wd);
    if (lane == 0) { redp[wv_] = rp; redw[wv_] = rw; }
    float sd = 0.0f;
    if (wv_ == 0) {
      float v = atomicAdd(&S_slot[16 * lane], 0.0f);  // coherent slot read
      sd = wave_reduce_sum(v);
    }
    __syncthreads();
    if (tid == 0) {
      float Sp   = redp[0] + redp[1] + redp[2] + redp[3];
      float Swpd = redw[0] + redw[1] + redw[2] + redw[3];
      float data_term = sd * (1.0f / ((float)B_N * (float)M_N));
      float wl = Swpd / (Sp + 1e-8f);
      float sparsity = Sp * (1.0f / ((float)M_N * (float)M_N));
      out[0] = data_term + LEN_C_ * wl + SP_C_ * sparsity;
    }
  }
}

extern "C" void kernel_launch(void* const* d_in, const int* in_sizes, int n_in,
                              void* d_out, int out_size, void* d_ws, size_t ws_size,
                              hipStream_t stream) {
  const float* data = (const float*)d_in[0];
  const float* w    = (const float*)d_in[1];
  const float* E    = (const float*)d_in[2];
  float* ws = (float*)d_ws;

  k_prep<<<2 * M_N, 256, 0, stream>>>(w, E, ws);
  k_main<<<GRID_MAIN, 256, 0, stream>>>(data, ws, (float*)d_out);
}

// Round 12
// 99.744 us; speedup vs baseline: 1.1484x; 1.0882x over previous
//
#include <hip/hip_runtime.h>
#include <math.h>

#define B_N 4096
#define M_N 256
#define D_N 256
#define ROWS 4                      // rows per k_main block
#define GRID_MAIN (B_N / ROWS)
#define NSLOT 64                    // partial-sum slots (1 per 64B line)
#define BLK_PER_SLOT (GRID_MAIN / NSLOT)

constexpr float TAU_   = 0.2f;
constexpr float LAM_   = 8.0f;
constexpr float TOPO_  = 0.5f;
constexpr float LEN_C_ = 0.01f;
constexpr float SP_C_  = 0.001f;
constexpr float LOG2E_ = 1.44269504088896340736f;
constexpr float KSC    = LOG2E_ / TAU_;
constexpr float KL     = LOG2E_ / LAM_;
constexpr float C0_    = 133.0f;    // fixed exponent center: dist ~18.5 -> sc ~133

// ws float layout:
// [4]          cnt2 (uint, single)
// [16..272)    degree[256]
// [512..768)   wnorm[256]
// [1024..1280) pPart[256]
// [1280..1536) wpdPart[256]
// [2048..3072) S_slot[64] strided 16 floats (64B line each)
// [4096..5120) cnt1[64]  (uint) strided 16
// [8192..73728) wT[256*256]  (D x M transpose)

__device__ __forceinline__ float wave_reduce_sum(float v) {
#pragma unroll
  for (int off = 1; off < 64; off <<= 1) v += __shfl_xor(v, off, 64);
  return v;
}

// sigmoid pair-combine step: s += (t+2)/( (t+1) + iv2*ep ), t = iv*es
__device__ __forceinline__ void rank_pair(float iv, float iv2, float es,
                                          float ep, float& s) {
  float t = iv * es;
  s = fmaf(t + 2.0f, __builtin_amdgcn_rcpf(fmaf(iv2, ep, t + 1.0f)), s);
}

// Dispatch 1: blocks 0..255 transpose w -> wT + wnorm + zero accumulators;
//             blocks 256..511 edge stats (direct proto-dist; self-contained).
__global__ __launch_bounds__(256) void k_prep(const float* __restrict__ w,
                                              const float* __restrict__ E,
                                              float* __restrict__ ws) {
  int tid = threadIdx.x;
  if (blockIdx.x < M_N) {
    float* wT = ws + 8192;
    int j = blockIdx.x, d = tid;
    float v = w[j * D_N + d];
    wT[d * M_N + j] = v;
    float s = wave_reduce_sum(v * v);
    __shared__ float red[4];
    if ((d & 63) == 0) red[d >> 6] = s;
    if (j == 0) {
      if (d < 16) ws[d] = 0.0f;                       // cnt2 etc.
      if (d < NSLOT) {
        ws[2048 + 16 * d] = 0.0f;                     // S_slot
        ((unsigned*)ws)[4096 + 16 * d] = 0u;          // cnt1
      }
    }
    __syncthreads();
    if (d == 0) ws[512 + j] = red[0] + red[1] + red[2] + red[3];
  } else {
    int j = blockIdx.x - M_N;
    int k = tid;
    __shared__ __align__(16) float swj[D_N];
    __shared__ float redp[4], redw[4];
    swj[k] = w[j * D_N + k];
    __syncthreads();

    float l = 0.5f * (E[j * M_N + k] + E[k * M_N + j]);
    float p = __builtin_amdgcn_rcpf(1.0f + __builtin_amdgcn_exp2f(-l * LOG2E_));
    if (k == j) p = 0.0f;

    float pd = 0.0f;
    const float4* wr = (const float4*)(w + (size_t)k * D_N);
    const float4* sw = (const float4*)swj;
#pragma unroll 8
    for (int i = 0; i < D_N / 4; i++) {
      float4 a = wr[i], b = sw[i];
      float dx = a.x - b.x, dy = a.y - b.y, dz = a.z - b.z, dw = a.w - b.w;
      pd += dx * dx + dy * dy + dz * dz + dw * dw;
    }

    float sp  = wave_reduce_sum(p);
    float spd = wave_reduce_sum(p * pd);
    if ((k & 63) == 0) { redp[k >> 6] = sp; redw[k >> 6] = spd; }
    __syncthreads();
    if (k == 0) {
      float tp = redp[0] + redp[1] + redp[2] + redp[3];
      float tw = redw[0] + redw[1] + redw[2] + redw[3];
      ws[16 + j]   = tp * (1.0f / (float)(M_N - 1));
      ws[1024 + j] = tp;
      ws[1280 + j] = tw;
    }
  }
}

// Dispatch 2: fused GEMM + soft-rank (R9 structure). GEMM uses an explicit
// 2-deep register double-buffer (16 loads in flight while consuming 16);
// __launch_bounds__(256,4) gives the allocator a 128-VGPR budget so the
// pipeline isn't squeezed back into serialized load clusters.
__global__ __launch_bounds__(256, 4) void k_main(const float* __restrict__ data,
                                                 float* __restrict__ ws,
                                                 float* __restrict__ out) {
  const float* wT     = ws + 8192;
  const float* wnorm  = ws + 512;
  const float* degree = ws + 16;
  float* S_slot  = ws + 2048;                 // stride 16 floats
  unsigned* cnt1 = (unsigned*)ws + 4096;      // stride 16
  unsigned* cnt2 = (unsigned*)ws + 4;

  __shared__ __align__(16) float ew[ROWS][M_N];   // e-values per row
  __shared__ __align__(16) float ewp[ROWS][M_N];  // pairs: [2p]=es, [2p+1]=ep
  __shared__ float rednrm[ROWS][4];
  __shared__ float snrm[ROWS];
  __shared__ float redf[4], redp[4], redw[4];
  __shared__ int isLast;

  const int tid  = threadIdx.x;
  const int wv_  = tid >> 6;
  const int lane = tid & 63;
  const int b0   = blockIdx.x * ROWS;

  // row norms
#pragma unroll
  for (int r = 0; r < ROWS; r++) {
    float x = data[(size_t)(b0 + r) * D_N + tid];
    float s = wave_reduce_sum(x * x);
    if (lane == 0) rednrm[r][wv_] = s;
  }
  __syncthreads();
  if (tid < ROWS)
    snrm[tid] = rednrm[tid][0] + rednrm[tid][1] + rednrm[tid][2] + rednrm[tid][3];

  // GEMM: x rows block-uniform (s_load float4); wT coalesced per thread.
  // Register double-buffer: batch g+1's 16 loads issued before batch g is
  // consumed -> waitcnt at consumption is vmcnt(16), 16+ loads in flight.
  const float4* x0 = (const float4*)(data + (size_t)(b0 + 0) * D_N);
  const float4* x1 = (const float4*)(data + (size_t)(b0 + 1) * D_N);
  const float4* x2 = (const float4*)(data + (size_t)(b0 + 2) * D_N);
  const float4* x3 = (const float4*)(data + (size_t)(b0 + 3) * D_N);
  const float* pw = wT + tid;

  float a0 = 0.f, a1 = 0.f, a2 = 0.f, a3 = 0.f;
  float wreg[2][16];
#pragma unroll
  for (int i = 0; i < 16; i++) wreg[0][i] = pw[(size_t)i * M_N];

#pragma unroll
  for (int g = 0; g < 16; g++) {
    const int cur = g & 1, nxt = cur ^ 1;
    if (g < 15) {
#pragma unroll
      for (int i = 0; i < 16; i++)
        wreg[nxt][i] = pw[(size_t)((g + 1) * 16 + i) * M_N];
    }
#pragma unroll
    for (int i4 = 0; i4 < 4; i4++) {
      int d4 = 4 * g + i4;
      float4 xa = x0[d4], xb = x1[d4], xc = x2[d4], xd = x3[d4];
      float w0 = wreg[cur][4 * i4 + 0], w1 = wreg[cur][4 * i4 + 1];
      float w2 = wreg[cur][4 * i4 + 2], w3 = wreg[cur][4 * i4 + 3];
      a0 = fmaf(xa.x, w0, a0); a0 = fmaf(xa.y, w1, a0);
      a0 = fmaf(xa.z, w2, a0); a0 = fmaf(xa.w, w3, a0);
      a1 = fmaf(xb.x, w0, a1); a1 = fmaf(xb.y, w1, a1);
      a1 = fmaf(xb.z, w2, a1); a1 = fmaf(xb.w, w3, a1);
      a2 = fmaf(xc.x, w0, a2); a2 = fmaf(xc.y, w1, a2);
      a2 = fmaf(xc.z, w2, a2); a2 = fmaf(xc.w, w3, a2);
      a3 = fmaf(xd.x, w0, a3); a3 = fmaf(xd.y, w1, a3);
      a3 = fmaf(xd.z, w2, a3); a3 = fmaf(xd.w, w3, a3);
    }
  }
  __syncthreads();   // snrm visible

  // distances + e-values (dist stays in registers for j = tid)
  float wn = wnorm[tid];
  float acc[ROWS] = {a0, a1, a2, a3};
  float dist[ROWS], iv[ROWS], iv2[ROWS];
#pragma unroll
  for (int r = 0; r < ROWS; r++) {
    float sq = snrm[r] - 2.0f * acc[r] + wn;
    dist[r] = sqrtf(fmaxf(sq, 0.0f));
    float sc = dist[r] * KSC;
    ew[r][tid] = __builtin_amdgcn_exp2f(sc - C0_);
    iv[r]      = __builtin_amdgcn_exp2f(C0_ - sc);
    iv2[r]     = iv[r] * iv[r];
  }
  __syncthreads();

  // hoisted pair terms: 4 rows x 128 pairs = 512 slots; thread does 2
#pragma unroll
  for (int h = 0; h < 2; h++) {
    int p  = tid + h * 256;
    int r  = p >> 7, idx = p & 127;
    float ea = ew[r][2 * idx], eb = ew[r][2 * idx + 1];
    ewp[r][2 * idx]     = ea + eb;
    ewp[r][2 * idx + 1] = ea * eb;
  }
  __syncthreads();

  // rank: per row, sum_k sigmoid((d_j-d_k)/tau), pair-combined
  float fj = 1.0f + TOPO_ * degree[tid];
  float tl = 0.0f;
#pragma unroll
  for (int r = 0; r < ROWS; r++) {
    float s = 0.0f;
    const float4* q4 = (const float4*)(&ewp[r][0]);
    float ivr = iv[r], iv2r = iv2[r];
#pragma unroll 8
    for (int k4 = 0; k4 < M_N / 4; k4++) {
      float4 q = q4[k4];                       // (es_a, ep_a, es_b, ep_b)
      rank_pair(ivr, iv2r, q.x, q.y, s);
      rank_pair(ivr, iv2r, q.z, q.w, s);
    }
    // diagonal contributes exactly 0.5; soft_rank-1 = s-0.5
    float nb = __builtin_amdgcn_exp2f((0.5f - s) * KL);
    tl = fmaf(nb * dist[r], fj, tl);
  }

  float bs = wave_reduce_sum(tl);
  if (lane == 0) redf[wv_] = bs;
  __syncthreads();
  if (tid == 0) {
    float tot = redf[0] + redf[1] + redf[2] + redf[3];
    int slot = (int)(blockIdx.x & (NSLOT - 1));
    float old = atomicAdd(&S_slot[16 * slot], tot);
    asm volatile("" : "+v"(old));   // consume: slot-add committed before cnt1
    int last = 0;
    unsigned t1 = atomicAdd(&cnt1[16 * slot], 1u);
    if (t1 == (unsigned)(BLK_PER_SLOT - 1)) {        // slot closed
      unsigned t2 = atomicAdd(cnt2, 1u);             // only 64 ever reach here
      last = (t2 == (unsigned)(NSLOT - 1)) ? 1 : 0;  // all slots closed
    }
    isLast = last;
  }
  __syncthreads();

  if (isLast) {
    float p  = ws[1024 + tid];
    float wd = ws[1280 + tid];
    float rp = wave_reduce_sum(p);
    float rw = wave_reduce_sum(wd);
    if (lane == 0) { redp[wv_] = rp; redw[wv_] = rw; }
    float sd = 0.0f;
    if (wv_ == 0) {
      float v = atomicAdd(&S_slot[16 * lane], 0.0f);  // coherent slot read
      sd = wave_reduce_sum(v);
    }
    __syncthreads();
    if (tid == 0) {
      float Sp   = redp[0] + redp[1] + redp[2] + redp[3];
      float Swpd = redw[0] + redw[1] + redw[2] + redw[3];
      float data_term = sd * (1.0f / ((float)B_N * (float)M_N));
      float wl = Swpd / (Sp + 1e-8f);
      float sparsity = Sp * (1.0f / ((float)M_N * (float)M_N));
      out[0] = data_term + LEN_C_ * wl + SP_C_ * sparsity;
    }
  }
}

extern "C" void kernel_launch(void* const* d_in, const int* in_sizes, int n_in,
                              void* d_out, int out_size, void* d_ws, size_t ws_size,
                              hipStream_t stream) {
  const float* data = (const float*)d_in[0];
  const float* w    = (const float*)d_in[1];
  const float* E    = (const float*)d_in[2];
  float* ws = (float*)d_ws;

  k_prep<<<2 * M_N, 256, 0, stream>>>(w, E, ws);
  k_main<<<GRID_MAIN, 256, 0, stream>>>(data, ws, (float*)d_out);
}